// Round 3
// baseline (605.215 us; speedup 1.0000x reference)
//
#include <hip/hip_runtime.h>

#define BATCH 65536

typedef float f32x4 __attribute__((ext_vector_type(4)));
typedef _Float16 f16x8 __attribute__((ext_vector_type(8)));

__device__ __forceinline__ float act_f(float x, float a0, float a1, float a2,
                                       float a3, float a4) {
  float ax = fabsf(x);
  float e = __builtin_amdgcn_exp2f(ax * -2.8853900817779268f);
  float th = (1.0f - e) * __builtin_amdgcn_rcpf(1.0f + e);
  th = copysignf(th, x);
  float arg = fmaf(a1, x, a2);
  float rev = arg * 0.15915494309189535f;
  rev -= floorf(rev);
  float s = __builtin_amdgcn_sinf(rev);
  return fmaf(a3, x, fmaf(a0 * th, s, a4));
}

// split + transpose weights: W[K][N] fp32 -> Wt_hi/lo[N][K] fp16 (packed)
__global__ __launch_bounds__(256) void splitT_k(const float* __restrict__ W,
                                                _Float16* __restrict__ hi,
                                                _Float16* __restrict__ lo,
                                                int K, int N) {
  const int i = blockIdx.x * 256 + threadIdx.x;
  if (i >= K * N) return;
  const int k = i / N, n = i % N;
  const float w = W[i];
  const _Float16 h = (_Float16)w;
  hi[(size_t)n * K + k] = h;
  lo[(size_t)n * K + k] = (_Float16)(w - (float)h);
}

__device__ __forceinline__ f32x4 mfma3(f16x8 ah, f16x8 al, f16x8 bh, f16x8 bl,
                                       f32x4 c) {
  c = __builtin_amdgcn_mfma_f32_16x16x32_f16(ah, bh, c, 0, 0, 0);
  c = __builtin_amdgcn_mfma_f32_16x16x32_f16(ah, bl, c, 0, 0, 0);
  c = __builtin_amdgcn_mfma_f32_16x16x32_f16(al, bh, c, 0, 0, 0);
  return c;
}

// k-loop for layers with A = h planes in LDS (hb[row*1024 + swz(k)] hi,
// +512 lo, k-index XOR-swizzled by (row&15)<<3). B = Wt[N][K] hi/lo from
// global (L2-hot weights), per-lane fragment loads, NO barriers.
template <int NT, int NK>
__device__ __forceinline__ void layer_h(const _Float16* __restrict__ hb,
                                        const _Float16* __restrict__ Bhi,
                                        const _Float16* __restrict__ Blo,
                                        int K, int wv, int m16, int quad,
                                        f32x4 acc[2][8]) {
#pragma unroll 2
  for (int it = 0; it < NK; ++it) {
    f16x8 bh[NT], bl[NT];
    const int nbase = (wv * NT * 16 + m16) * K + it * 32 + quad * 8;
#pragma unroll
    for (int tn = 0; tn < NT; ++tn) {
      bh[tn] = *(const f16x8*)(Bhi + nbase + tn * 16 * K);
      bl[tn] = *(const f16x8*)(Blo + nbase + tn * 16 * K);
    }
    f16x8 ah[2], al[2];
    const int ks = (it * 32 + quad * 8) ^ (m16 << 3);
#pragma unroll
    for (int tm = 0; tm < 2; ++tm) {
      const int ro = (tm * 16 + m16) * 1024;
      ah[tm] = *(const f16x8*)&hb[ro + ks];
      al[tm] = *(const f16x8*)&hb[ro + 512 + ks];
    }
#pragma unroll
    for (int tn = 0; tn < NT; ++tn)
#pragma unroll
      for (int tm = 0; tm < 2; ++tm)
        acc[tm][tn] = mfma3(ah[tm], al[tm], bh[tn], bl[tn], acc[tm][tn]);
  }
}

// epilogue: bias + activation; TO_H: split to h hi/lo planes (swizzled k),
// else write fp32 logits [32][256] at hb base.
template <int NT, bool TO_H>
__device__ __forceinline__ void epilogue(f32x4 acc[2][8],
                                         const float* __restrict__ bias,
                                         const float* __restrict__ ap, int wv,
                                         int m16, int quad, _Float16* hb) {
#pragma unroll
  for (int tn = 0; tn < NT; ++tn) {
    const int col = wv * NT * 16 + tn * 16 + m16;
    const float bs = bias[col];
    const float p0 = ap[col * 5 + 0];
    const float p1 = ap[col * 5 + 1];
    const float p2 = ap[col * 5 + 2];
    const float p3 = ap[col * 5 + 3];
    const float p4 = ap[col * 5 + 4];
#pragma unroll
    for (int tm = 0; tm < 2; ++tm)
#pragma unroll
      for (int r = 0; r < 4; ++r) {
        const int row = tm * 16 + quad * 4 + r;
        const float y = act_f(acc[tm][tn][r] + bs, p0, p1, p2, p3, p4);
        if (TO_H) {
          const int cs = col ^ ((row & 15) << 3);
          const _Float16 h = (_Float16)y;
          hb[row * 1024 + cs] = h;
          hb[row * 1024 + 512 + cs] = (_Float16)(y - (float)h);
        } else {
          ((float*)hb)[row * 256 + col] = y;
        }
      }
  }
}

__global__ __launch_bounds__(256, 2) void fused_net(
    const float* __restrict__ data, const _Float16* __restrict__ w1hi,
    const _Float16* __restrict__ w1lo, const float* __restrict__ b1,
    const float* __restrict__ a1p, const _Float16* __restrict__ w2hi,
    const _Float16* __restrict__ w2lo, const float* __restrict__ b2,
    const float* __restrict__ a2p, const _Float16* __restrict__ w3hi,
    const _Float16* __restrict__ w3lo, const float* __restrict__ b3,
    const float* __restrict__ a3p, float* __restrict__ out) {
  // 64 KB: h planes [32 rows][hi 512 | lo 512] halfs, row stride 2048 B.
  // data tile (fp32 [32][256], swizzled) and logits (fp32 [32][256]) alias it.
  __shared__ __align__(16) _Float16 hb[32 * 1024];

  const int tid = threadIdx.x;
  const int wv = tid >> 6, lane = tid & 63;
  const int m16 = lane & 15, quad = lane >> 4;
  const int row0 = blockIdx.x * 32;

  float* dptr = (float*)hb;

  // ---- stage data tile 32x256 fp32 (swizzled k) ----
  {
    const float* dg = data + (size_t)row0 * 256;
#pragma unroll
    for (int i = 0; i < 8; ++i) {
      const int idx = tid + i * 256;
      const int r = idx >> 6, c4 = (idx & 63) << 2;
      const f32x4 v = *(const f32x4*)(dg + r * 256 + c4);
      const int cs = c4 ^ ((r & 15) << 3);
      *(f32x4*)&dptr[r * 256 + cs] = v;
    }
  }
  __syncthreads();

  f32x4 acc[2][8];
  const f32x4 zero = {0.f, 0.f, 0.f, 0.f};

  // ---- layer 1: A = fp32 data in LDS (split in-register), K=256, N=512 ----
#pragma unroll
  for (int i = 0; i < 2; ++i)
#pragma unroll
    for (int j = 0; j < 8; ++j) acc[i][j] = zero;
#pragma unroll 2
  for (int it = 0; it < 8; ++it) {
    f16x8 bh[8], bl[8];
    const int nbase = (wv * 128 + m16) * 256 + it * 32 + quad * 8;
#pragma unroll
    for (int tn = 0; tn < 8; ++tn) {
      bh[tn] = *(const f16x8*)(w1hi + nbase + tn * 16 * 256);
      bl[tn] = *(const f16x8*)(w1lo + nbase + tn * 16 * 256);
    }
    f16x8 ah[2], al[2];
    const int ks = (it * 32 + quad * 8) ^ (m16 << 3);
#pragma unroll
    for (int tm = 0; tm < 2; ++tm) {
      const int ro = (tm * 16 + m16) * 256;
      const f32x4 x0 = *(const f32x4*)&dptr[ro + ks];
      const f32x4 x1 = *(const f32x4*)&dptr[ro + ks + 4];
#pragma unroll
      for (int j = 0; j < 4; ++j) {
        const _Float16 h0 = (_Float16)x0[j];
        ah[tm][j] = h0;
        al[tm][j] = (_Float16)(x0[j] - (float)h0);
        const _Float16 h1 = (_Float16)x1[j];
        ah[tm][4 + j] = h1;
        al[tm][4 + j] = (_Float16)(x1[j] - (float)h1);
      }
    }
#pragma unroll
    for (int tn = 0; tn < 8; ++tn)
#pragma unroll
      for (int tm = 0; tm < 2; ++tm)
        acc[tm][tn] = mfma3(ah[tm], al[tm], bh[tn], bl[tn], acc[tm][tn]);
  }
  __syncthreads();  // all waves done reading data tile
  epilogue<8, true>(acc, b1, a1p, wv, m16, quad, hb);
  __syncthreads();

  // ---- layer 2: A = h1 planes, K=512, N=512 (in-place h2 over h1) ----
#pragma unroll
  for (int i = 0; i < 2; ++i)
#pragma unroll
    for (int j = 0; j < 8; ++j) acc[i][j] = zero;
  layer_h<8, 16>(hb, w2hi, w2lo, 512, wv, m16, quad, acc);
  __syncthreads();  // all waves done reading h1
  epilogue<8, true>(acc, b2, a2p, wv, m16, quad, hb);
  __syncthreads();

  // ---- layer 3: A = h2 planes, K=512, N=256 -> logits in LDS ----
#pragma unroll
  for (int i = 0; i < 2; ++i)
#pragma unroll
    for (int j = 0; j < 8; ++j) acc[i][j] = zero;
  layer_h<4, 16>(hb, w3hi, w3lo, 512, wv, m16, quad, acc);
  __syncthreads();  // all waves done reading h2
  epilogue<4, false>(acc, b3, a3p, wv, m16, quad, hb);
  __syncthreads();

  // ---- softmax over 256 cols, one wave per row, 8 rows/wave ----
  const float* lg = (const float*)hb;
#pragma unroll
  for (int r8 = 0; r8 < 8; ++r8) {
    const int row = wv * 8 + r8;
    f32x4 v = *(const f32x4*)&lg[row * 256 + lane * 4];
    float m = fmaxf(fmaxf(v[0], v[1]), fmaxf(v[2], v[3]));
#pragma unroll
    for (int off = 32; off > 0; off >>= 1) m = fmaxf(m, __shfl_xor(m, off));
    f32x4 e;
    float s = 0.f;
#pragma unroll
    for (int j = 0; j < 4; ++j) {
      e[j] = __builtin_amdgcn_exp2f((v[j] - m) * 1.4426950408889634f);
      s += e[j];
    }
#pragma unroll
    for (int off = 32; off > 0; off >>= 1) s += __shfl_xor(s, off);
    const float inv = __builtin_amdgcn_rcpf(s);
#pragma unroll
    for (int j = 0; j < 4; ++j) e[j] *= inv;
    *(f32x4*)(out + (size_t)(row0 + row) * 256 + lane * 4) = e;
  }
}

extern "C" void kernel_launch(void* const* d_in, const int* in_sizes, int n_in,
                              void* d_out, int out_size, void* d_ws,
                              size_t ws_size, hipStream_t stream) {
  const float* data = (const float*)d_in[0];
  const float* W1 = (const float*)d_in[1];
  const float* b1 = (const float*)d_in[2];
  const float* a1 = (const float*)d_in[3];
  const float* W2 = (const float*)d_in[4];
  const float* b2 = (const float*)d_in[5];
  const float* a2 = (const float*)d_in[6];
  const float* W3 = (const float*)d_in[7];
  const float* b3 = (const float*)d_in[8];
  const float* a3 = (const float*)d_in[9];
  float* out = (float*)d_out;

  char* ws = (char*)d_ws;
  const size_t KB = 1024;
  _Float16* w1hi = (_Float16*)(ws + 0 * KB);     // Wt1[512][256]
  _Float16* w1lo = (_Float16*)(ws + 256 * KB);
  _Float16* w2hi = (_Float16*)(ws + 512 * KB);   // Wt2[512][512]
  _Float16* w2lo = (_Float16*)(ws + 1024 * KB);
  _Float16* w3hi = (_Float16*)(ws + 1536 * KB);  // Wt3[256][512]
  _Float16* w3lo = (_Float16*)(ws + 1792 * KB);

  splitT_k<<<(256 * 512 + 255) / 256, 256, 0, stream>>>(W1, w1hi, w1lo, 256, 512);
  splitT_k<<<(512 * 512 + 255) / 256, 256, 0, stream>>>(W2, w2hi, w2lo, 512, 512);
  splitT_k<<<(512 * 256 + 255) / 256, 256, 0, stream>>>(W3, w3hi, w3lo, 512, 256);

  fused_net<<<BATCH / 32, 256, 0, stream>>>(data, w1hi, w1lo, b1, a1, w2hi,
                                            w2lo, b2, a2, w3hi, w3lo, b3, a3,
                                            out);
}

// Round 4
// 438.947 us; speedup vs baseline: 1.3788x; 1.3788x over previous
//
#include <hip/hip_runtime.h>

#define BATCH 65536

typedef float f32x4 __attribute__((ext_vector_type(4)));
typedef _Float16 f16x8 __attribute__((ext_vector_type(8)));

__device__ __forceinline__ void async_ld16(const void* g, void* l) {
  __builtin_amdgcn_global_load_lds(
      (const __attribute__((address_space(1))) void*)g,
      (__attribute__((address_space(3))) void*)l, 16, 0, 0);
}

__device__ __forceinline__ float act_f(float x, float a0, float a1, float a2,
                                       float a3, float a4) {
  float ax = fabsf(x);
  float e = __builtin_amdgcn_exp2f(ax * -2.8853900817779268f);
  float th = (1.0f - e) * __builtin_amdgcn_rcpf(1.0f + e);
  th = copysignf(th, x);
  float arg = fmaf(a1, x, a2);
  float rev = arg * 0.15915494309189535f;
  rev -= floorf(rev);
  float s = __builtin_amdgcn_sinf(rev);
  return fmaf(a3, x, fmaf(a0 * th, s, a4));
}

// split + transpose weights: W[K][N] fp32 -> Wt_hi/lo[N][K] fp16 (packed)
__global__ __launch_bounds__(256) void splitT_k(const float* __restrict__ W,
                                                _Float16* __restrict__ hi,
                                                _Float16* __restrict__ lo,
                                                int K, int N) {
  const int i = blockIdx.x * 256 + threadIdx.x;
  if (i >= K * N) return;
  const int k = i / N, n = i % N;
  const float w = W[i];
  const _Float16 h = (_Float16)w;
  hi[(size_t)n * K + k] = h;
  lo[(size_t)n * K + k] = (_Float16)(w - (float)h);
}

__device__ __forceinline__ f32x4 mfma3(f16x8 ah, f16x8 al, f16x8 bh, f16x8 bl,
                                       f32x4 c) {
  c = __builtin_amdgcn_mfma_f32_16x16x32_f16(ah, bh, c, 0, 0, 0);
  c = __builtin_amdgcn_mfma_f32_16x16x32_f16(ah, bl, c, 0, 0, 0);
  c = __builtin_amdgcn_mfma_f32_16x16x32_f16(al, bh, c, 0, 0, 0);
  return c;
}

// C = A @ B, block tile 64 rows x 256 cols, BK=32. A: fp32 [M][K] (AF32,
// LDS-staged then split in-register) or fp16 hi/lo planes [M][K]. B: Wt[N][K]
// fp16 hi/lo. 3-product compensation (Ahi*Bhi + Ahi*Blo + Alo*Bhi, fp32 acc).
// 4 waves as 2x2; wave tile 32x128 (2 m-tiles x 8 n-tiles).
// Epilogue: bias + activation; FINAL -> fp32 out (stride 256), else hi/lo
// fp16 planes (stride N).
template <bool AF32, bool FINAL>
__global__ __launch_bounds__(256, 4) void gemm_act(
    const float* __restrict__ Af, const _Float16* __restrict__ Ahi,
    const _Float16* __restrict__ Alo, const _Float16* __restrict__ Bhi,
    const _Float16* __restrict__ Blo, const float* __restrict__ bias,
    const float* __restrict__ ap, _Float16* __restrict__ Chi,
    _Float16* __restrict__ Clo, float* __restrict__ Cout, int K, int N) {
  // sA: 8 KB = fp32 A tile 64x32 (AF32) or 2 fp16 planes 64x32 each
  // sB: 32 KB = 2 fp16 planes 256x32
  __shared__ __align__(16) _Float16 sA[4096];
  __shared__ __align__(16) _Float16 sB[16384];

  const int tid = threadIdx.x;
  const int wv = tid >> 6;
  const int lane = tid & 63;
  const int wm = wv >> 1, wn = wv & 1;
  const int m16 = lane & 15, quad = lane >> 4;
  const int col0 = blockIdx.x * 256;
  const int row0 = blockIdx.y * 64;

  f32x4 acc[2][8];
  const f32x4 zero = {0.f, 0.f, 0.f, 0.f};
#pragma unroll
  for (int i = 0; i < 2; ++i)
#pragma unroll
    for (int j = 0; j < 8; ++j) acc[i][j] = zero;

  const int nk = K >> 5;
  for (int kt = 0; kt < nk; ++kt) {
    const int k0 = kt << 5;
    // ---- stage A ----
    if (AF32) {
      // 8 chunks of 1KB (8 rows x 128B); wave stages chunks 2wv, 2wv+1
      float* sAf = (float*)sA;
#pragma unroll
      for (int t = 0; t < 2; ++t) {
        const int c = wv * 2 + t;
        const int r = c * 8 + (lane >> 3);
        const size_t ga = (size_t)(row0 + r) * K + k0 + (lane & 7) * 4;
        async_ld16(Af + ga, (void*)&sAf[c * 256]);
      }
    } else {
      // per plane: 4 chunks (16 rows x 64B); wave stages chunk wv of each
      const int r = wv * 16 + (lane >> 2);
      const size_t ga = (size_t)(row0 + r) * K + k0 + (lane & 3) * 8;
      async_ld16(Ahi + ga, (void*)&sA[wv * 512]);
      async_ld16(Alo + ga, (void*)&sA[2048 + wv * 512]);
    }
    // ---- stage B: per plane 16 chunks (16 cols x 64B); wave stages 4 ----
#pragma unroll
    for (int t = 0; t < 4; ++t) {
      const int c = wv * 4 + t;
      const int col = c * 16 + (lane >> 2);
      const size_t gb = (size_t)(col0 + col) * K + k0 + (lane & 3) * 8;
      async_ld16(Bhi + gb, (void*)&sB[c * 512]);
      async_ld16(Blo + gb, (void*)&sB[8192 + c * 512]);
    }
    __syncthreads();

    // ---- A fragments ----
    f16x8 ah[2], al[2];
#pragma unroll
    for (int tm = 0; tm < 2; ++tm) {
      const int arow = wm * 32 + tm * 16 + m16;
      if (AF32) {
        const float* pa = (const float*)sA + arow * 32 + quad * 8;
        const f32x4 x0 = *(const f32x4*)pa;
        const f32x4 x1 = *(const f32x4*)(pa + 4);
#pragma unroll
        for (int j = 0; j < 4; ++j) {
          const _Float16 h0 = (_Float16)x0[j];
          ah[tm][j] = h0;
          al[tm][j] = (_Float16)(x0[j] - (float)h0);
          const _Float16 h1 = (_Float16)x1[j];
          ah[tm][4 + j] = h1;
          al[tm][4 + j] = (_Float16)(x1[j] - (float)h1);
        }
      } else {
        ah[tm] = *(const f16x8*)&sA[arow * 32 + quad * 8];
        al[tm] = *(const f16x8*)&sA[2048 + arow * 32 + quad * 8];
      }
    }
    // ---- B fragments + MFMA, n-tiles streamed ----
#pragma unroll
    for (int tn = 0; tn < 8; ++tn) {
      const int bcol = wn * 128 + tn * 16 + m16;
      const f16x8 bh = *(const f16x8*)&sB[bcol * 32 + quad * 8];
      const f16x8 bl = *(const f16x8*)&sB[8192 + bcol * 32 + quad * 8];
#pragma unroll
      for (int tm = 0; tm < 2; ++tm)
        acc[tm][tn] = mfma3(ah[tm], al[tm], bh, bl, acc[tm][tn]);
    }
    __syncthreads();
  }

  // ---- epilogue: C/D layout col=lane&15, row=quad*4+reg ----
#pragma unroll
  for (int tn = 0; tn < 8; ++tn) {
    const int col = col0 + wn * 128 + tn * 16 + m16;
    const float bs = bias[col];
    const float p0 = ap[col * 5 + 0];
    const float p1 = ap[col * 5 + 1];
    const float p2 = ap[col * 5 + 2];
    const float p3 = ap[col * 5 + 3];
    const float p4 = ap[col * 5 + 4];
#pragma unroll
    for (int tm = 0; tm < 2; ++tm) {
      const int row = row0 + wm * 32 + tm * 16 + quad * 4;
#pragma unroll
      for (int r = 0; r < 4; ++r) {
        const float y = act_f(acc[tm][tn][r] + bs, p0, p1, p2, p3, p4);
        if (FINAL) {
          Cout[(size_t)(row + r) * 256 + col] = y;
        } else {
          const size_t o = (size_t)(row + r) * N + col;
          const _Float16 h = (_Float16)y;
          Chi[o] = h;
          Clo[o] = (_Float16)(y - (float)h);
        }
      }
    }
  }
}

// in-place softmax over 256 columns; one wave per row, 4 rows/block
__global__ __launch_bounds__(256) void softmax_rows(float* __restrict__ io) {
  const int wv = threadIdx.x >> 6, lane = threadIdx.x & 63;
  const size_t row = (size_t)blockIdx.x * 4 + wv;
  f32x4* p = (f32x4*)(io + row * 256);
  f32x4 v = p[lane];
  float m = fmaxf(fmaxf(v[0], v[1]), fmaxf(v[2], v[3]));
#pragma unroll
  for (int off = 32; off > 0; off >>= 1) m = fmaxf(m, __shfl_xor(m, off));
  f32x4 e;
  float s = 0.f;
#pragma unroll
  for (int j = 0; j < 4; ++j) {
    e[j] = __builtin_amdgcn_exp2f((v[j] - m) * 1.4426950408889634f);
    s += e[j];
  }
#pragma unroll
  for (int off = 32; off > 0; off >>= 1) s += __shfl_xor(s, off);
  const float inv = __builtin_amdgcn_rcpf(s);
#pragma unroll
  for (int j = 0; j < 4; ++j) e[j] *= inv;
  p[lane] = e;
}

extern "C" void kernel_launch(void* const* d_in, const int* in_sizes, int n_in,
                              void* d_out, int out_size, void* d_ws,
                              size_t ws_size, hipStream_t stream) {
  const float* data = (const float*)d_in[0];
  const float* W1 = (const float*)d_in[1];
  const float* b1 = (const float*)d_in[2];
  const float* a1 = (const float*)d_in[3];
  const float* W2 = (const float*)d_in[4];
  const float* b2 = (const float*)d_in[5];
  const float* a2 = (const float*)d_in[6];
  const float* W3 = (const float*)d_in[7];
  const float* b3 = (const float*)d_in[8];
  const float* a3 = (const float*)d_in[9];
  float* out = (float*)d_out;

  char* ws = (char*)d_ws;
  const size_t KB = 1024, MB = 1024 * 1024;
  _Float16* w1hi = (_Float16*)(ws + 0 * KB);     // Wt1[512][256]
  _Float16* w1lo = (_Float16*)(ws + 256 * KB);
  _Float16* w2hi = (_Float16*)(ws + 512 * KB);   // Wt2[512][512]
  _Float16* w2lo = (_Float16*)(ws + 1024 * KB);
  _Float16* w3hi = (_Float16*)(ws + 1536 * KB);  // Wt3[256][512]
  _Float16* w3lo = (_Float16*)(ws + 1792 * KB);
  // h1 hi/lo: 65536x512 fp16 = 64 MB each; h2lo 64 MB; h2hi lives in d_out
  // (row i of h2hi = bytes [1024i,1024i+1024) = row i of out; GEMM3 blocks
  // are full-N and row-disjoint -> alias-safe)
  _Float16* h1hi = (_Float16*)(ws + 2 * MB);
  _Float16* h1lo = (_Float16*)(ws + 2 * MB + (size_t)BATCH * 512 * 2);
  _Float16* h2lo = (_Float16*)(ws + 2 * MB + (size_t)BATCH * 512 * 4);
  _Float16* h2hi = (_Float16*)d_out;

  splitT_k<<<(256 * 512 + 255) / 256, 256, 0, stream>>>(W1, w1hi, w1lo, 256, 512);
  splitT_k<<<(512 * 512 + 255) / 256, 256, 0, stream>>>(W2, w2hi, w2lo, 512, 512);
  splitT_k<<<(512 * 256 + 255) / 256, 256, 0, stream>>>(W3, w3hi, w3lo, 512, 256);

  // grid: x = N-tiles (fastest -> strip-mates dispatch-adjacent, L3-hot A),
  //       y = 64-row M-strips
  gemm_act<true, false><<<dim3(2, BATCH / 64), 256, 0, stream>>>(
      data, nullptr, nullptr, w1hi, w1lo, b1, a1, h1hi, h1lo, nullptr, 256, 512);
  gemm_act<false, false><<<dim3(2, BATCH / 64), 256, 0, stream>>>(
      nullptr, h1hi, h1lo, w2hi, w2lo, b2, a2, h2hi, h2lo, nullptr, 512, 512);
  gemm_act<false, true><<<dim3(1, BATCH / 64), 256, 0, stream>>>(
      nullptr, h2hi, h2lo, w3hi, w3lo, b3, a3, nullptr, nullptr, out, 512, 256);

  softmax_rows<<<BATCH / 4, 256, 0, stream>>>(out);
}